// Round 6
// baseline (648.989 us; speedup 1.0000x reference)
//
#include <hip/hip_runtime.h>
#include <hip/hip_cooperative_groups.h>
#include <stdint.h>

namespace cg = cooperative_groups;

typedef unsigned long long u64;
typedef __attribute__((ext_vector_type(8))) short bf16x8;
typedef __attribute__((ext_vector_type(4))) float f32x4;

#define BATCH 512
#define FEAT 256
#define ENC 2048
#define HID 4096
#define CLS 1000
#define KTOT 12288      // 3 * 4096
#define NBLK 512        // cooperative grid: 2 blocks/CU guaranteed
#define NSPLIT 16
#define KSPLIT 768
#define PARTLD 1024

// ws offsets
#define OFF_ENC2   0
#define OFF_ACT2   131072
#define OFF_TABLE  917504
#define OFF_COUNTS 1703936
#define OFF_AG     1753088
#define OFF_WT     14336000
#define OFF_PART   39501824
#define PART_BYTES (16ull * 512 * 1024 * 4)

// ---------- fp32 -> bf16 RNE ----------
static __device__ inline unsigned short f2bf(float f) {
    unsigned u = __float_as_uint(f);
    return (unsigned short)((u + 0x7FFFu + ((u >> 16) & 1u)) >> 16);
}

// ---------- async global->LDS, 16B/lane ----------
static __device__ inline void gld16(const void* g, void* s) {
    __builtin_amdgcn_global_load_lds((const __attribute__((address_space(1))) void*)g,
                                     (__attribute__((address_space(3))) void*)s, 16, 0, 0);
}

// ================= kernel 1: fused prep = encode | scan | twt (R4 version, occ 70%) ====
__global__ void __launch_bounds__(256)
k_prep(const float* __restrict__ x, u64* __restrict__ enc2,
       const float* __restrict__ W0, const float* __restrict__ W1,
       const float* __restrict__ W2,
       uint16_t* __restrict__ table, int* __restrict__ counts,
       const float* __restrict__ out_w, short* __restrict__ wt) {
    __shared__ short tile[64 * 68];
    __shared__ int cnt4[4];
    int bid = blockIdx.x;
    int t = threadIdx.x;
    int lane = t & 63;
    int wv = t >> 6;

    if (bid < 512) {
        int wid = bid * 4 + wv;
        int f = wid >> 3, bg = wid & 7;
        float v = x[(size_t)(bg * 64 + lane) * FEAT + f];
        v = fminf(fmaxf(v, 0.0f), 1.0f);
        int lev = (int)rintf(v * 255.0f);                // RNE == jnp.round
        unsigned gray = (unsigned)(lev ^ (lev >> 1));
        u64 w = 0;
        #pragma unroll
        for (int bit = 0; bit < 8; ++bit) {
            u64 m = __ballot((gray >> bit) & 1u);
            if (lane == bit) w = m;
        }
        if (lane < 8) enc2[(size_t)bg * ENC + f * 8 + lane] = w;
        return;
    }
    if (bid < 5632) {
        if (t < 4) cnt4[t] = 0;
        __syncthreads();
        int wsid = (bid - 512) * 4 + wv;
        int row, base, cidx;
        if (wsid < HID) { row = wsid; base = 0; cidx = wv; }
        else {
            int w2 = wsid - HID;
            row = HID + (w2 >> 1);
            base = (w2 & 1) * 2048;
            cidx = wv >> 1;
        }
        const float* Wr;
        if (row < HID)          Wr = W0 + (size_t)row * ENC;
        else if (row < 2 * HID) Wr = W1 + (size_t)(row - HID) * HID + base;
        else                    Wr = W2 + (size_t)(row - 2 * HID) * HID + base;
        const uint4* p4 = (const uint4*)Wr;
        uint4 v[8];
        #pragma unroll
        for (int j = 0; j < 8; ++j) v[j] = p4[j * 64 + lane];
        uint16_t* te = table + (size_t)row * 32;
        #pragma unroll
        for (int j = 0; j < 8; ++j) {
            unsigned a0 = v[j].x, a1 = v[j].y, a2 = v[j].z, a3 = v[j].w;
            if (a0 | a1 | a2 | a3) {
                int col0 = base + j * 256 + lane * 4;
                if (a0) { int s = atomicAdd(&cnt4[cidx], 1);
                          te[s] = (uint16_t)((unsigned)col0       | ((a0 >> 16) & 0x8000u)); }
                if (a1) { int s = atomicAdd(&cnt4[cidx], 1);
                          te[s] = (uint16_t)((unsigned)(col0 + 1) | ((a1 >> 16) & 0x8000u)); }
                if (a2) { int s = atomicAdd(&cnt4[cidx], 1);
                          te[s] = (uint16_t)((unsigned)(col0 + 2) | ((a2 >> 16) & 0x8000u)); }
                if (a3) { int s = atomicAdd(&cnt4[cidx], 1);
                          te[s] = (uint16_t)((unsigned)(col0 + 3) | ((a3 >> 16) & 0x8000u)); }
            }
        }
        __syncthreads();
        if (lane == 0) counts[row] = cnt4[cidx];
        return;
    }
    {
        int b2 = bid - 5632;
        int kt = b2 % 192, ct = b2 / 192;
        int k0 = kt * 64, c0 = ct * 64;
        {
            int rrow = t >> 4, c4 = t & 15;
            int c = c0 + c4 * 4;
            #pragma unroll
            for (int rd = 0; rd < 4; ++rd) {
                int kl = rd * 16 + rrow;
                float4 vv;
                if (c < CLS) vv = *(const float4*)&out_w[(size_t)(k0 + kl) * CLS + c];
                else { vv.x = vv.y = vv.z = vv.w = 0.0f; }
                short* d = &tile[kl * 68 + c4 * 4];
                d[0] = (short)f2bf(vv.x); d[1] = (short)f2bf(vv.y);
                d[2] = (short)f2bf(vv.z); d[3] = (short)f2bf(vv.w);
            }
        }
        __syncthreads();
        {
            int chunk = t & 7, cl2 = t >> 3;
            #pragma unroll
            for (int rd = 0; rd < 2; ++rd) {
                int c_local = rd * 32 + cl2;
                int c = c0 + c_local;
                unsigned s8[8];
                #pragma unroll
                for (int j = 0; j < 8; ++j)
                    s8[j] = (unsigned)(unsigned short)tile[(chunk * 8 + j) * 68 + c_local];
                uint4 pk;
                pk.x = s8[0] | (s8[1] << 16);
                pk.y = s8[2] | (s8[3] << 16);
                pk.z = s8[4] | (s8[5] << 16);
                pk.w = s8[6] | (s8[7] << 16);
                *(uint4*)&wt[(size_t)c * KTOT + k0 + ((chunk ^ (c & 7)) * 8)] = pk;
            }
        }
    }
}

// ================= kernel 2: fused net = layers(LDS) | expand | gemm | reduce =========
__global__ void __launch_bounds__(256, 2)
k_net(const u64* __restrict__ enc2, u64* __restrict__ act2,
      const uint16_t* __restrict__ table, const int* __restrict__ counts,
      short* __restrict__ Ag, const short* __restrict__ wt,
      float* __restrict__ out, float* __restrict__ part, int use_part) {
    cg::grid_group grid = cg::this_grid();
    __shared__ __attribute__((aligned(16))) char lds[32768];
    int bid = blockIdx.x, t = threadIdx.x;
    int lane = t & 63, wv = t >> 6;

    // ---- phase 1-3: sparse layers; block pins one bg, prev slice lives in LDS ----
    int bg = bid & 7, gb = bid >> 3;     // 64 block-groups per bg
    for (int l = 0; l < 3; ++l) {
        const char* sbase = (l == 0)
            ? (const char*)(enc2 + (size_t)bg * ENC)
            : (const char*)(act2 + ((size_t)(l - 1) * 8 + bg) * HID);
        int nbytes = (l == 0) ? ENC * 8 : HID * 8;     // 16 KB / 32 KB
        for (int it = 0; it < nbytes; it += 4096)
            gld16(sbase + it + t * 16, lds + it + t * 16);
        __syncthreads();
        const u64* plds = (const u64*)lds;
        const uint16_t* tbl = table + (size_t)l * HID * 32;
        const int* cnt_arr = counts + (size_t)l * HID;
        for (int n = gb * 4 + wv; n < HID; n += 256) {   // 16 neurons per wave
            const uint4* tq = (const uint4*)(tbl + (size_t)n * 32);
            int cnt = cnt_arr[n];
            int z = 0;
            #pragma unroll
            for (int q = 0; q < 4; ++q) {
                uint4 e4 = tq[q];
                unsigned es[4] = {e4.x, e4.y, e4.z, e4.w};
                #pragma unroll
                for (int h = 0; h < 4; ++h) {
                    #pragma unroll
                    for (int s2 = 0; s2 < 2; ++s2) {
                        int e = q * 8 + h * 2 + s2;
                        if (e < cnt) {
                            unsigned ent = (es[h] >> (s2 * 16)) & 0xFFFFu;
                            u64 w = plds[ent & 0x7FFFu];      // LDS broadcast
                            int bit = (int)((w >> lane) & 1ull);
                            z += (ent & 0x8000u) ? -bit : bit;
                        }
                    }
                }
            }
            u64 res = __ballot(z >= 4);
            if (lane == 0) act2[((size_t)l * 8 + bg) * HID + n] = res;
        }
        grid.sync();
    }

    // ---- phase 4: expand activation bits -> bf16 Ag (swizzled) ----
    for (int it = 0; it < 6; ++it) {
        int idx = bid * 256 + t + it * (NBLK * 256);     // 786432 exactly
        int b = idx / 1536;
        int rem = idx - b * 1536;
        int l = rem >> 9;
        int chunk = rem & 511;
        int bgx = b >> 6, bl = b & 63;
        const u64* src = act2 + ((size_t)l * 8 + bgx) * HID + chunk * 8;
        unsigned sh[8];
        #pragma unroll
        for (int j = 0; j < 8; ++j) sh[j] = ((src[j] >> bl) & 1ull) ? 0x3F80u : 0u;
        int g = chunk & 7, c64 = chunk >> 3;
        short* dst = Ag + (size_t)b * KTOT + l * HID + c64 * 64 + ((g ^ (b & 7)) * 8);
        uint4 pk;
        pk.x = sh[0] | (sh[1] << 16);
        pk.y = sh[2] | (sh[3] << 16);
        pk.z = sh[4] | (sh[5] << 16);
        pk.w = sh[6] | (sh[7] << 16);
        *(uint4*)dst = pk;
    }
    grid.sync();

    // ---- phase 5: GEMM (512 tiles = grid exactly) ----
    {
        short* As = (short*)lds;
        short* Bs = (short*)(lds + 16384);
        int mt = bid & 3, nt = (bid >> 2) & 7, ks = bid >> 5;
        int waveM = wv & 1, waveN = wv >> 1;
        int quad = lane >> 4, cl = lane & 15;
        f32x4 acc[4][4] = {};
        const char* Ab = (const char*)(Ag + (size_t)mt * 128 * KTOT + ks * KSPLIT);
        const char* Bb = (const char*)(wt + (size_t)nt * 128 * KTOT + ks * KSPLIT);
        int r = t >> 3, sub = t & 7;
        for (int kk = 0; kk < KSPLIT; kk += 64) {
            #pragma unroll
            for (int rd = 0; rd < 4; ++rd) {
                size_t go = (size_t)(r + rd * 32) * (KTOT * 2) + kk * 2 + sub * 16;
                gld16(Ab + go, &As[(t + rd * 256) * 8]);
                gld16(Bb + go, &Bs[(t + rd * 256) * 8]);
            }
            __syncthreads();
            #pragma unroll
            for (int s = 0; s < 2; ++s) {
                int xr = ((s * 4 + quad) ^ (cl & 7)) * 8;
                bf16x8 af[4], bfr[4];
                #pragma unroll
                for (int mf = 0; mf < 4; ++mf)
                    af[mf] = *(const bf16x8*)&As[(waveM * 64 + mf * 16 + cl) * 64 + xr];
                #pragma unroll
                for (int nf = 0; nf < 4; ++nf)
                    bfr[nf] = *(const bf16x8*)&Bs[(waveN * 64 + nf * 16 + cl) * 64 + xr];
                #pragma unroll
                for (int mf = 0; mf < 4; ++mf)
                    #pragma unroll
                    for (int nf = 0; nf < 4; ++nf)
                        acc[mf][nf] = __builtin_amdgcn_mfma_f32_16x16x32_bf16(
                            af[mf], bfr[nf], acc[mf][nf], 0, 0, 0);
            }
            __syncthreads();
        }
        if (use_part) {
            float* pbase = part + (size_t)ks * (BATCH * PARTLD);
            #pragma unroll
            for (int mf = 0; mf < 4; ++mf)
                #pragma unroll
                for (int nf = 0; nf < 4; ++nf) {
                    int cp = nt * 128 + waveN * 64 + nf * 16 + cl;
                    #pragma unroll
                    for (int rr = 0; rr < 4; ++rr) {
                        int mg = mt * 128 + waveM * 64 + mf * 16 + quad * 4 + rr;
                        pbase[(size_t)mg * PARTLD + cp] = acc[mf][nf][rr];
                    }
                }
        } else {
            #pragma unroll
            for (int mf = 0; mf < 4; ++mf)
                #pragma unroll
                for (int nf = 0; nf < 4; ++nf) {
                    int cp = nt * 128 + waveN * 64 + nf * 16 + cl;
                    if (cp < CLS) {
                        #pragma unroll
                        for (int rr = 0; rr < 4; ++rr) {
                            int mg = mt * 128 + waveM * 64 + mf * 16 + quad * 4 + rr;
                            atomicAdd(&out[(size_t)mg * CLS + cp], acc[mf][nf][rr]);
                        }
                    }
                }
        }
    }
    grid.sync();

    // ---- phase 6: reduce split-K partials ----
    if (use_part) {
        for (int it = 0; it < 4; ++it) {
            int idx = bid * 256 + t + it * (NBLK * 256);
            if (idx < BATCH * CLS) {
                int b = idx / CLS, c = idx - b * CLS;
                float s = 0.0f;
                #pragma unroll
                for (int sp = 0; sp < NSPLIT; ++sp)
                    s += part[((size_t)sp * BATCH + b) * PARTLD + c];
                out[idx] = s;
            }
        }
    }
}

extern "C" void kernel_launch(void* const* d_in, const int* in_sizes, int n_in,
                              void* d_out, int out_size, void* d_ws, size_t ws_size,
                              hipStream_t stream) {
    const float* x     = (const float*)d_in[0];
    const float* W0    = (const float*)d_in[1];
    const float* W1    = (const float*)d_in[2];
    const float* W2    = (const float*)d_in[3];
    const float* out_w = (const float*)d_in[4];
    float* out = (float*)d_out;
    char* ws = (char*)d_ws;

    u64*      enc2   = (u64*)(ws + OFF_ENC2);
    u64*      act2   = (u64*)(ws + OFF_ACT2);
    uint16_t* table  = (uint16_t*)(ws + OFF_TABLE);
    int*      counts = (int*)(ws + OFF_COUNTS);
    short*    Ag     = (short*)(ws + OFF_AG);
    short*    wt     = (short*)(ws + OFF_WT);
    float*    part   = (float*)(ws + OFF_PART);

    int use_part = (ws_size >= (size_t)OFF_PART + PART_BYTES) ? 1 : 0;

    hipLaunchKernelGGL(k_prep, dim3(8704), dim3(256), 0, stream,
                       x, enc2, W0, W1, W2, table, counts, out_w, wt);
    if (!use_part)
        hipMemsetAsync(d_out, 0, (size_t)BATCH * CLS * sizeof(float), stream);

    const u64* enc2c = enc2;
    const uint16_t* tablec = table;
    const int* countsc = counts;
    const short* wtc = wt;
    void* args[] = {(void*)&enc2c, (void*)&act2, (void*)&tablec, (void*)&countsc,
                    (void*)&Ag, (void*)&wtc, (void*)&out, (void*)&part, (void*)&use_part};
    hipLaunchCooperativeKernel((const void*)k_net, dim3(NBLK), dim3(256), args, 0, stream);
}

// Round 8
// 399.312 us; speedup vs baseline: 1.6253x; 1.6253x over previous
//
#include <hip/hip_runtime.h>
#include <stdint.h>

typedef unsigned long long u64;
typedef __attribute__((ext_vector_type(8))) short bf16x8;
typedef __attribute__((ext_vector_type(4))) float f32x4;
typedef __attribute__((ext_vector_type(4))) unsigned u32x4;

#define BATCH 512
#define FEAT 256
#define ENC 2048
#define HID 4096
#define CLS 1000
#define KTOT 12288      // 3 * 4096
#define NSPLIT 16
#define KSPLIT 768
#define PARTLD 1024

// ws offsets
#define OFF_ENC2   0
#define OFF_ACT2   131072
#define OFF_TABLE  917504
#define OFF_COUNTS 1703936
#define OFF_AG     1753088
#define OFF_WT     14336000
#define OFF_PART   39501824
#define PART_BYTES (16ull * 512 * 1024 * 4)
#define OFF_GCNT   (OFF_PART + PART_BYTES)       // 32 ints for split-K completion

// ---------- fp32 -> bf16 RNE ----------
static __device__ inline unsigned short f2bf(float f) {
    unsigned u = __float_as_uint(f);
    return (unsigned short)((u + 0x7FFFu + ((u >> 16) & 1u)) >> 16);
}

// ---------- async global->LDS, 16B/lane ----------
static __device__ inline void gld16(const void* g, void* s) {
    __builtin_amdgcn_global_load_lds((const __attribute__((address_space(1))) void*)g,
                                     (__attribute__((address_space(3))) void*)s, 16, 0, 0);
}

// ================= kernel 1: fused prep = encode | scan | twt =================
// blocks [0,512): encode (+gcnt zero)  [512,5632): scan   [5632,8704): twt
__global__ void __launch_bounds__(256)
k_prep(const float* __restrict__ x, u64* __restrict__ enc2,
       const float* __restrict__ W0, const float* __restrict__ W1,
       const float* __restrict__ W2,
       uint16_t* __restrict__ table, int* __restrict__ counts,
       const float* __restrict__ out_w, short* __restrict__ wt,
       int* gcnt) {
    __shared__ short tile[64 * 68];
    __shared__ int cnt4[4];
    int bid = blockIdx.x;
    int t = threadIdx.x;
    int lane = t & 63;
    int wv = t >> 6;

    if (bid < 512) {
        if (bid == 0 && t < 32 && gcnt) gcnt[t] = 0;   // zero split-K counters
        int wid = bid * 4 + wv;
        int f = wid >> 3, bg = wid & 7;
        float v = x[(size_t)(bg * 64 + lane) * FEAT + f];
        v = fminf(fmaxf(v, 0.0f), 1.0f);
        int lev = (int)rintf(v * 255.0f);                // RNE == jnp.round
        unsigned gray = (unsigned)(lev ^ (lev >> 1));
        u64 w = 0;
        #pragma unroll
        for (int bit = 0; bit < 8; ++bit) {
            u64 m = __ballot((gray >> bit) & 1u);
            if (lane == bit) w = m;
        }
        if (lane < 8) enc2[(size_t)bg * ENC + f * 8 + lane] = w;
        return;
    }
    if (bid < 5632) {
        // ---- scan: nontemporal streaming reads (W never re-read) ----
        if (t < 4) cnt4[t] = 0;
        __syncthreads();
        int wsid = (bid - 512) * 4 + wv;
        int row, base, cidx;
        if (wsid < HID) { row = wsid; base = 0; cidx = wv; }
        else {
            int w2 = wsid - HID;
            row = HID + (w2 >> 1);
            base = (w2 & 1) * 2048;
            cidx = wv >> 1;
        }
        const float* Wr;
        if (row < HID)          Wr = W0 + (size_t)row * ENC;
        else if (row < 2 * HID) Wr = W1 + (size_t)(row - HID) * HID + base;
        else                    Wr = W2 + (size_t)(row - 2 * HID) * HID + base;
        const u32x4* p4 = (const u32x4*)Wr;
        u32x4 v[8];
        #pragma unroll
        for (int j = 0; j < 8; ++j) v[j] = __builtin_nontemporal_load(p4 + j * 64 + lane);
        uint16_t* te = table + (size_t)row * 32;
        #pragma unroll
        for (int j = 0; j < 8; ++j) {
            unsigned a0 = v[j].x, a1 = v[j].y, a2 = v[j].z, a3 = v[j].w;
            if (a0 | a1 | a2 | a3) {
                int col0 = base + j * 256 + lane * 4;
                if (a0) { int s = atomicAdd(&cnt4[cidx], 1);
                          te[s] = (uint16_t)((unsigned)col0       | ((a0 >> 16) & 0x8000u)); }
                if (a1) { int s = atomicAdd(&cnt4[cidx], 1);
                          te[s] = (uint16_t)((unsigned)(col0 + 1) | ((a1 >> 16) & 0x8000u)); }
                if (a2) { int s = atomicAdd(&cnt4[cidx], 1);
                          te[s] = (uint16_t)((unsigned)(col0 + 2) | ((a2 >> 16) & 0x8000u)); }
                if (a3) { int s = atomicAdd(&cnt4[cidx], 1);
                          te[s] = (uint16_t)((unsigned)(col0 + 3) | ((a3 >> 16) & 0x8000u)); }
            }
        }
        __syncthreads();
        if (lane == 0) counts[row] = cnt4[cidx];
        return;
    }
    {
        // ---- twt: transpose+convert out_w -> wt bf16 (swizzled); nt reads ----
        int b2 = bid - 5632;
        int kt = b2 % 192, ct = b2 / 192;
        int k0 = kt * 64, c0 = ct * 64;
        {
            int rrow = t >> 4, c4 = t & 15;
            int c = c0 + c4 * 4;
            #pragma unroll
            for (int rd = 0; rd < 4; ++rd) {
                int kl = rd * 16 + rrow;
                f32x4 vv;
                if (c < CLS)
                    vv = __builtin_nontemporal_load(
                        (const f32x4*)&out_w[(size_t)(k0 + kl) * CLS + c]);
                else { vv.x = 0.0f; vv.y = 0.0f; vv.z = 0.0f; vv.w = 0.0f; }
                short* d = &tile[kl * 68 + c4 * 4];
                d[0] = (short)f2bf(vv.x); d[1] = (short)f2bf(vv.y);
                d[2] = (short)f2bf(vv.z); d[3] = (short)f2bf(vv.w);
            }
        }
        __syncthreads();
        {
            int chunk = t & 7, cl2 = t >> 3;
            #pragma unroll
            for (int rd = 0; rd < 2; ++rd) {
                int c_local = rd * 32 + cl2;
                int c = c0 + c_local;
                unsigned s8[8];
                #pragma unroll
                for (int j = 0; j < 8; ++j)
                    s8[j] = (unsigned)(unsigned short)tile[(chunk * 8 + j) * 68 + c_local];
                uint4 pk;
                pk.x = s8[0] | (s8[1] << 16);
                pk.y = s8[2] | (s8[3] << 16);
                pk.z = s8[4] | (s8[5] << 16);
                pk.w = s8[6] | (s8[7] << 16);
                *(uint4*)&wt[(size_t)c * KTOT + k0 + ((chunk ^ (c & 7)) * 8)] = pk;
            }
        }
    }
}

// ---------- expand one (b,chunk) item of layer l: bits -> bf16 Ag (swizzled) ----------
static __device__ inline void expand_item(const u64* __restrict__ act2,
                                          short* __restrict__ Ag, int l, int eidx) {
    int b = eidx >> 9, chunk = eidx & 511;
    int bg = b >> 6, bl = b & 63;
    const u64* src = act2 + ((size_t)l * 8 + bg) * HID + chunk * 8;
    unsigned sh[8];
    #pragma unroll
    for (int j = 0; j < 8; ++j) sh[j] = ((src[j] >> bl) & 1ull) ? 0x3F80u : 0u;
    int g = chunk & 7, c64 = chunk >> 3;
    short* dst = Ag + (size_t)b * KTOT + l * HID + c64 * 64 + ((g ^ (b & 7)) * 8);
    uint4 pk;
    pk.x = sh[0] | (sh[1] << 16);
    pk.y = sh[2] | (sh[3] << 16);
    pk.z = sh[4] | (sh[5] << 16);
    pk.w = sh[6] | (sh[7] << 16);
    *(uint4*)dst = pk;
}

// ================= kernel 2: layer (+ rider blocks expanding previous layer) ==========
__global__ void k_layer(const u64* __restrict__ prev2, int Kstride,
                        const uint16_t* __restrict__ table_l, const int* __restrict__ counts_l,
                        u64* __restrict__ actout,
                        const u64* __restrict__ act2, short* __restrict__ Ag, int exp_l) {
    int bid = blockIdx.x;
    if (bid >= 8192) {                                  // expand rider
        expand_item(act2, Ag, exp_l, (bid - 8192) * 256 + threadIdx.x);
        return;
    }
    int wid = __builtin_amdgcn_readfirstlane(bid * 4 + (threadIdx.x >> 6));
    int lane = threadIdx.x & 63;
    int n = wid >> 3, bg = wid & 7;
    const u64* prow = prev2 + (size_t)bg * Kstride;
    const uint4* tq = (const uint4*)(table_l + (size_t)n * 32);
    int cnt = counts_l[n];
    int z = 0;
    #pragma unroll
    for (int q = 0; q < 4; ++q) {
        uint4 e4 = tq[q];
        unsigned es[4] = {e4.x, e4.y, e4.z, e4.w};
        #pragma unroll
        for (int h = 0; h < 4; ++h) {
            #pragma unroll
            for (int s2 = 0; s2 < 2; ++s2) {
                int e = q * 8 + h * 2 + s2;
                if (e < cnt) {
                    unsigned ent = (es[h] >> (s2 * 16)) & 0xFFFFu;
                    u64 w = prow[ent & 0x7FFFu];         // uniform addr -> broadcast
                    int bit = (int)((w >> lane) & 1ull);
                    z += (ent & 0x8000u) ? -bit : bit;
                }
            }
        }
    }
    u64 res = __ballot(z >= 4);
    if (lane == 0) actout[(size_t)bg * HID + n] = res;
}

// ================= kernel 3: leftover expand (layer 2) ================================
__global__ void k_expand1(const u64* __restrict__ act2, short* __restrict__ Ag, int l) {
    expand_item(act2, Ag, l, blockIdx.x * 256 + threadIdx.x);
}

// ================= kernel 4: GEMM, XCD-grouped split-K, fused winner reduce ===========
template<int MODE>   // 0: partials + winner reduce, 1: atomics into out
__global__ void __launch_bounds__(256)
k_gemm(const short* __restrict__ Ag, const short* __restrict__ wt,
       float* __restrict__ out, float* __restrict__ part, int* __restrict__ gcnt) {
    __shared__ __attribute__((aligned(16))) short As[128 * 64];
    __shared__ __attribute__((aligned(16))) short Bs[128 * 64];
    __shared__ int s_old;
    int bid = blockIdx.x;
    // XCD-L2 grouping: all 32 blocks of one ks land on XCD ks%8 (bid%8 round-robin)
    int ks = bid & 15, mt = (bid >> 4) & 3, nt = bid >> 6;
    int tid = threadIdx.x, lane = tid & 63;
    int wv = tid >> 6, waveM = wv & 1, waveN = wv >> 1;
    int quad = lane >> 4, cl = lane & 15;
    f32x4 acc[4][4] = {};
    const char* Ab = (const char*)(Ag + (size_t)mt * 128 * KTOT + ks * KSPLIT);
    const char* Bb = (const char*)(wt + (size_t)nt * 128 * KTOT + ks * KSPLIT);
    int r = tid >> 3, sub = tid & 7;
    for (int kk = 0; kk < KSPLIT; kk += 64) {
        #pragma unroll
        for (int rd = 0; rd < 4; ++rd) {
            size_t go = (size_t)(r + rd * 32) * (KTOT * 2) + kk * 2 + sub * 16;
            gld16(Ab + go, &As[(tid + rd * 256) * 8]);
            gld16(Bb + go, &Bs[(tid + rd * 256) * 8]);
        }
        __syncthreads();
        #pragma unroll
        for (int s = 0; s < 2; ++s) {
            int xr = ((s * 4 + quad) ^ (cl & 7)) * 8;
            bf16x8 af[4], bfr[4];
            #pragma unroll
            for (int mf = 0; mf < 4; ++mf)
                af[mf] = *(const bf16x8*)&As[(waveM * 64 + mf * 16 + cl) * 64 + xr];
            #pragma unroll
            for (int nf = 0; nf < 4; ++nf)
                bfr[nf] = *(const bf16x8*)&Bs[(waveN * 64 + nf * 16 + cl) * 64 + xr];
            #pragma unroll
            for (int mf = 0; mf < 4; ++mf)
                #pragma unroll
                for (int nf = 0; nf < 4; ++nf)
                    acc[mf][nf] = __builtin_amdgcn_mfma_f32_16x16x32_bf16(
                        af[mf], bfr[nf], acc[mf][nf], 0, 0, 0);
        }
        __syncthreads();
    }
    if (MODE == 0) {
        float* pbase = part + (size_t)ks * (BATCH * PARTLD);
        #pragma unroll
        for (int mf = 0; mf < 4; ++mf)
            #pragma unroll
            for (int nf = 0; nf < 4; ++nf) {
                int cp = nt * 128 + waveN * 64 + nf * 16 + cl;
                #pragma unroll
                for (int rr = 0; rr < 4; ++rr) {
                    int mg = mt * 128 + waveM * 64 + mf * 16 + quad * 4 + rr;
                    pbase[(size_t)mg * PARTLD + cp] = acc[mf][nf][rr];
                }
            }
        // ---- winner-block split-K reduction (release/acquire via threadfence) ----
        __threadfence();
        if (tid == 0) s_old = atomicAdd(&gcnt[mt * 8 + nt], 1);
        __syncthreads();
        if (s_old == 15) {
            __threadfence();
            for (int i = tid; i < 128 * 32; i += 256) {
                int mr = mt * 128 + (i >> 5);
                int cp = nt * 128 + (i & 31) * 4;
                if (cp < CLS) {
                    float4 s = {0.f, 0.f, 0.f, 0.f};
                    #pragma unroll
                    for (int sp = 0; sp < NSPLIT; ++sp) {
                        float4 v = *(const float4*)&part[((size_t)sp * BATCH + mr) * PARTLD + cp];
                        s.x += v.x; s.y += v.y; s.z += v.z; s.w += v.w;
                    }
                    *(float4*)&out[(size_t)mr * CLS + cp] = s;
                }
            }
        }
    } else {
        #pragma unroll
        for (int mf = 0; mf < 4; ++mf)
            #pragma unroll
            for (int nf = 0; nf < 4; ++nf) {
                int cp = nt * 128 + waveN * 64 + nf * 16 + cl;
                if (cp < CLS) {
                    #pragma unroll
                    for (int rr = 0; rr < 4; ++rr) {
                        int mg = mt * 128 + waveM * 64 + mf * 16 + quad * 4 + rr;
                        atomicAdd(&out[(size_t)mg * CLS + cp], acc[mf][nf][rr]);
                    }
                }
            }
    }
}

extern "C" void kernel_launch(void* const* d_in, const int* in_sizes, int n_in,
                              void* d_out, int out_size, void* d_ws, size_t ws_size,
                              hipStream_t stream) {
    const float* x     = (const float*)d_in[0];
    const float* W0    = (const float*)d_in[1];
    const float* W1    = (const float*)d_in[2];
    const float* W2    = (const float*)d_in[3];
    const float* out_w = (const float*)d_in[4];
    float* out = (float*)d_out;
    char* ws = (char*)d_ws;

    u64*      enc2   = (u64*)(ws + OFF_ENC2);
    u64*      act2   = (u64*)(ws + OFF_ACT2);
    uint16_t* table  = (uint16_t*)(ws + OFF_TABLE);
    int*      counts = (int*)(ws + OFF_COUNTS);
    short*    Ag     = (short*)(ws + OFF_AG);
    short*    wt     = (short*)(ws + OFF_WT);
    float*    part   = (float*)(ws + OFF_PART);
    int*      gcnt   = (int*)(ws + OFF_GCNT);

    int use_part = (ws_size >= (size_t)OFF_GCNT + 128) ? 1 : 0;

    hipLaunchKernelGGL(k_prep, dim3(8704), dim3(256), 0, stream,
                       x, enc2, W0, W1, W2, table, counts, out_w, wt,
                       use_part ? gcnt : (int*)nullptr);
    if (!use_part)
        (void)hipMemsetAsync(d_out, 0, (size_t)BATCH * CLS * sizeof(float), stream);

    hipLaunchKernelGGL(k_layer, dim3(8192), dim3(256), 0, stream,
                       enc2, ENC, table, counts, act2, act2, Ag, -1);
    hipLaunchKernelGGL(k_layer, dim3(9216), dim3(256), 0, stream,
                       act2, HID, table + (size_t)HID * 32, counts + HID,
                       act2 + 8 * HID, act2, Ag, 0);
    hipLaunchKernelGGL(k_layer, dim3(9216), dim3(256), 0, stream,
                       act2 + 8 * HID, HID, table + (size_t)2 * HID * 32, counts + 2 * HID,
                       act2 + 16 * HID, act2, Ag, 1);
    hipLaunchKernelGGL(k_expand1, dim3(1024), dim3(256), 0, stream, act2, Ag, 2);
    if (use_part) {
        hipLaunchKernelGGL((k_gemm<0>), dim3(512), dim3(256), 0, stream,
                           Ag, wt, out, part, gcnt);
    } else {
        hipLaunchKernelGGL((k_gemm<1>), dim3(512), dim3(256), 0, stream,
                           Ag, wt, out, part, gcnt);
    }
}

// Round 9
// 299.303 us; speedup vs baseline: 2.1683x; 1.3341x over previous
//
#include <hip/hip_runtime.h>
#include <stdint.h>

typedef unsigned long long u64;
typedef __attribute__((ext_vector_type(8))) short bf16x8;
typedef __attribute__((ext_vector_type(4))) float f32x4;
typedef __attribute__((ext_vector_type(4))) unsigned u32x4;

#define BATCH 512
#define FEAT 256
#define ENC 2048
#define HID 4096
#define CLS 1000
#define KTOT 12288      // 3 * 4096
#define NSPLIT 16
#define KSPLIT 768
#define PARTLD 1024

// ws offsets (Ag eliminated)
#define OFF_ENC2   0
#define OFF_ACT2   131072
#define OFF_TABLE  917504
#define OFF_COUNTS 1703936
#define OFF_WT     1753088
#define OFF_PART   26918912
#define PART_BYTES (16ull * 512 * 1024 * 4)
#define WS_NEED    (OFF_PART + PART_BYTES)

// ---------- fp32 -> bf16 RNE ----------
static __device__ inline unsigned short f2bf(float f) {
    unsigned u = __float_as_uint(f);
    return (unsigned short)((u + 0x7FFFu + ((u >> 16) & 1u)) >> 16);
}

// ---------- async global->LDS, 16B/lane ----------
static __device__ inline void gld16(const void* g, void* s) {
    __builtin_amdgcn_global_load_lds((const __attribute__((address_space(1))) void*)g,
                                     (__attribute__((address_space(3))) void*)s, 16, 0, 0);
}

// ================= kernel 1: fused prep = encode | scan | twt =================
// blocks [0,512): encode   [512,5632): scan   [5632,8704): twt
__global__ void __launch_bounds__(256)
k_prep(const float* __restrict__ x, u64* __restrict__ enc2,
       const float* __restrict__ W0, const float* __restrict__ W1,
       const float* __restrict__ W2,
       uint16_t* __restrict__ table, int* __restrict__ counts,
       const float* __restrict__ out_w, short* __restrict__ wt) {
    __shared__ short tile[64 * 68];
    __shared__ int cnt4[4];
    int bid = blockIdx.x;
    int t = threadIdx.x;
    int lane = t & 63;
    int wv = t >> 6;

    if (bid < 512) {
        int wid = bid * 4 + wv;
        int f = wid >> 3, bg = wid & 7;
        float v = x[(size_t)(bg * 64 + lane) * FEAT + f];
        v = fminf(fmaxf(v, 0.0f), 1.0f);
        int lev = (int)rintf(v * 255.0f);                // RNE == jnp.round
        unsigned gray = (unsigned)(lev ^ (lev >> 1));
        u64 w = 0;
        #pragma unroll
        for (int bit = 0; bit < 8; ++bit) {
            u64 m = __ballot((gray >> bit) & 1u);
            if (lane == bit) w = m;
        }
        if (lane < 8) enc2[(size_t)bg * ENC + f * 8 + lane] = w;
        return;
    }
    if (bid < 5632) {
        // ---- scan: nontemporal streaming reads; LDS-atomic slot compaction ----
        if (t < 4) cnt4[t] = 0;
        __syncthreads();
        int wsid = (bid - 512) * 4 + wv;
        int row, base, cidx;
        if (wsid < HID) { row = wsid; base = 0; cidx = wv; }
        else {
            int w2 = wsid - HID;
            row = HID + (w2 >> 1);
            base = (w2 & 1) * 2048;
            cidx = wv >> 1;
        }
        const float* Wr;
        if (row < HID)          Wr = W0 + (size_t)row * ENC;
        else if (row < 2 * HID) Wr = W1 + (size_t)(row - HID) * HID + base;
        else                    Wr = W2 + (size_t)(row - 2 * HID) * HID + base;
        const u32x4* p4 = (const u32x4*)Wr;
        u32x4 v[8];
        #pragma unroll
        for (int j = 0; j < 8; ++j) v[j] = __builtin_nontemporal_load(p4 + j * 64 + lane);
        uint16_t* te = table + (size_t)row * 32;
        #pragma unroll
        for (int j = 0; j < 8; ++j) {
            unsigned a0 = v[j].x, a1 = v[j].y, a2 = v[j].z, a3 = v[j].w;
            if (a0 | a1 | a2 | a3) {
                int col0 = base + j * 256 + lane * 4;
                if (a0) { int s = atomicAdd(&cnt4[cidx], 1);
                          te[s] = (uint16_t)((unsigned)col0       | ((a0 >> 16) & 0x8000u)); }
                if (a1) { int s = atomicAdd(&cnt4[cidx], 1);
                          te[s] = (uint16_t)((unsigned)(col0 + 1) | ((a1 >> 16) & 0x8000u)); }
                if (a2) { int s = atomicAdd(&cnt4[cidx], 1);
                          te[s] = (uint16_t)((unsigned)(col0 + 2) | ((a2 >> 16) & 0x8000u)); }
                if (a3) { int s = atomicAdd(&cnt4[cidx], 1);
                          te[s] = (uint16_t)((unsigned)(col0 + 3) | ((a3 >> 16) & 0x8000u)); }
            }
        }
        __syncthreads();
        if (lane == 0) counts[row] = cnt4[cidx];
        return;
    }
    {
        // ---- twt: transpose+convert out_w -> wt bf16 (swizzled) ----
        int b2 = bid - 5632;
        int kt = b2 % 192, ct = b2 / 192;
        int k0 = kt * 64, c0 = ct * 64;
        {
            int rrow = t >> 4, c4 = t & 15;
            int c = c0 + c4 * 4;
            #pragma unroll
            for (int rd = 0; rd < 4; ++rd) {
                int kl = rd * 16 + rrow;
                f32x4 vv;
                if (c < CLS)
                    vv = __builtin_nontemporal_load(
                        (const f32x4*)&out_w[(size_t)(k0 + kl) * CLS + c]);
                else { vv.x = 0.0f; vv.y = 0.0f; vv.z = 0.0f; vv.w = 0.0f; }
                short* d = &tile[kl * 68 + c4 * 4];
                d[0] = (short)f2bf(vv.x); d[1] = (short)f2bf(vv.y);
                d[2] = (short)f2bf(vv.z); d[3] = (short)f2bf(vv.w);
            }
        }
        __syncthreads();
        {
            int chunk = t & 7, cl2 = t >> 3;
            #pragma unroll
            for (int rd = 0; rd < 2; ++rd) {
                int c_local = rd * 32 + cl2;
                int c = c0 + c_local;
                unsigned s8[8];
                #pragma unroll
                for (int j = 0; j < 8; ++j)
                    s8[j] = (unsigned)(unsigned short)tile[(chunk * 8 + j) * 68 + c_local];
                uint4 pk;
                pk.x = s8[0] | (s8[1] << 16);
                pk.y = s8[2] | (s8[3] << 16);
                pk.z = s8[4] | (s8[5] << 16);
                pk.w = s8[6] | (s8[7] << 16);
                *(uint4*)&wt[(size_t)c * KTOT + k0 + ((chunk ^ (c & 7)) * 8)] = pk;
            }
        }
    }
}

// ================= kernel 2: layer, lanes = batch, uniform vector loads ==============
__global__ void k_layer(const u64* __restrict__ prev2, int Kstride,
                        const uint16_t* __restrict__ table_l, const int* __restrict__ counts_l,
                        u64* __restrict__ actout) {
    int wid = __builtin_amdgcn_readfirstlane(blockIdx.x * 4 + (threadIdx.x >> 6));
    int lane = threadIdx.x & 63;
    int n = wid >> 3, bg = wid & 7;
    const u64* prow = prev2 + (size_t)bg * Kstride;
    const uint4* tq = (const uint4*)(table_l + (size_t)n * 32);
    int cnt = counts_l[n];
    int z = 0;
    #pragma unroll
    for (int q = 0; q < 4; ++q) {
        uint4 e4 = tq[q];
        unsigned es[4] = {e4.x, e4.y, e4.z, e4.w};
        #pragma unroll
        for (int h = 0; h < 4; ++h) {
            #pragma unroll
            for (int s2 = 0; s2 < 2; ++s2) {
                int e = q * 8 + h * 2 + s2;
                if (e < cnt) {
                    unsigned ent = (es[h] >> (s2 * 16)) & 0xFFFFu;
                    u64 w = prow[ent & 0x7FFFu];         // uniform addr -> broadcast
                    int bit = (int)((w >> lane) & 1ull);
                    z += (ent & 0x8000u) ? -bit : bit;
                }
            }
        }
    }
    u64 res = __ballot(z >= 4);
    if (lane == 0) actout[(size_t)bg * HID + n] = res;
}

// ================= kernel 3: GEMM, A expanded from BITS in-kernel =====================
// act2: (3, 8, 4096) u64 (bits over batch). B: wt pre-swizzled bf16.
template<int MODE>   // 0: partial stores, 1: atomics into out
__global__ void __launch_bounds__(256)
k_gemm(const u64* __restrict__ act2, const short* __restrict__ wt,
       float* __restrict__ out, float* __restrict__ part) {
    __shared__ __attribute__((aligned(16))) short As[128 * 64];
    __shared__ __attribute__((aligned(16))) short Bs[128 * 64];
    int bid = blockIdx.x;
    int mt = bid & 3, nt = (bid >> 2) & 7, ks = bid >> 5;   // R2-proven mapping
    int tid = threadIdx.x, lane = tid & 63;
    int wv = tid >> 6, waveM = wv & 1, waveN = wv >> 1;
    int quad = lane >> 4, cl = lane & 15;
    f32x4 acc[4][4] = {};
    const char* Bb = (const char*)(wt + (size_t)nt * 128 * KTOT + ks * KSPLIT);
    int r = tid >> 3, sub = tid & 7;
    for (int kk = 0; kk < KSPLIT; kk += 64) {
        // ---- B: async DMA 16 KB ----
        #pragma unroll
        for (int rd = 0; rd < 4; ++rd) {
            size_t go = (size_t)(r + rd * 32) * (KTOT * 2) + kk * 2 + sub * 16;
            gld16(Bb + go, &Bs[(tid + rd * 256) * 8]);
        }
        // ---- A: expand 1 KB of bits -> 16 KB bf16 in LDS (XOR-swizzled) ----
        {
            int kabs = ks * KSPLIT + kk;          // 64-aligned, within one layer
            int l = kabs >> 12, nk = kabs & 4095;
            #pragma unroll
            for (int i = 0; i < 4; ++i) {
                int item = i * 256 + tid;         // 1024 items: 128 rows x 8 groups
                int rr = item >> 3, g = item & 7;
                const u64* w8 = act2 + ((size_t)(l * 8 + mt * 2 + (rr >> 6))) * HID + nk + g * 8;
                int bl = rr & 63;
                unsigned sh[8];
                #pragma unroll
                for (int j = 0; j < 8; ++j)
                    sh[j] = (unsigned)((w8[j] >> bl) & 1ull) * 0x3F80u;
                uint4 pk;
                pk.x = sh[0] | (sh[1] << 16);
                pk.y = sh[2] | (sh[3] << 16);
                pk.z = sh[4] | (sh[5] << 16);
                pk.w = sh[6] | (sh[7] << 16);
                *(uint4*)&As[rr * 64 + ((g ^ (rr & 7)) * 8)] = pk;
            }
        }
        __syncthreads();
        #pragma unroll
        for (int s = 0; s < 2; ++s) {
            int xr = ((s * 4 + quad) ^ (cl & 7)) * 8;
            bf16x8 af[4], bfr[4];
            #pragma unroll
            for (int mf = 0; mf < 4; ++mf)
                af[mf] = *(const bf16x8*)&As[(waveM * 64 + mf * 16 + cl) * 64 + xr];
            #pragma unroll
            for (int nf = 0; nf < 4; ++nf)
                bfr[nf] = *(const bf16x8*)&Bs[(waveN * 64 + nf * 16 + cl) * 64 + xr];
            #pragma unroll
            for (int mf = 0; mf < 4; ++mf)
                #pragma unroll
                for (int nf = 0; nf < 4; ++nf)
                    acc[mf][nf] = __builtin_amdgcn_mfma_f32_16x16x32_bf16(
                        af[mf], bfr[nf], acc[mf][nf], 0, 0, 0);
        }
        __syncthreads();
    }
    if (MODE == 0) {
        float* pbase = part + (size_t)ks * (BATCH * PARTLD);
        #pragma unroll
        for (int mf = 0; mf < 4; ++mf)
            #pragma unroll
            for (int nf = 0; nf < 4; ++nf) {
                int cp = nt * 128 + waveN * 64 + nf * 16 + cl;
                #pragma unroll
                for (int rr = 0; rr < 4; ++rr) {
                    int mg = mt * 128 + waveM * 64 + mf * 16 + quad * 4 + rr;
                    pbase[(size_t)mg * PARTLD + cp] = acc[mf][nf][rr];
                }
            }
    } else {
        #pragma unroll
        for (int mf = 0; mf < 4; ++mf)
            #pragma unroll
            for (int nf = 0; nf < 4; ++nf) {
                int cp = nt * 128 + waveN * 64 + nf * 16 + cl;
                if (cp < CLS) {
                    #pragma unroll
                    for (int rr = 0; rr < 4; ++rr) {
                        int mg = mt * 128 + waveM * 64 + mf * 16 + quad * 4 + rr;
                        atomicAdd(&out[(size_t)mg * CLS + cp], acc[mf][nf][rr]);
                    }
                }
            }
    }
}

// ================= kernel 4: reduce split-K partials into out ====================
__global__ void k_reduce(const float* __restrict__ part, float* __restrict__ out) {
    int idx = blockIdx.x * blockDim.x + threadIdx.x;
    if (idx >= BATCH * CLS) return;
    int b = idx / CLS, c = idx - b * CLS;
    float s = 0.0f;
    #pragma unroll
    for (int sp = 0; sp < NSPLIT; ++sp)
        s += part[((size_t)sp * BATCH + b) * PARTLD + c];
    out[idx] = s;
}

extern "C" void kernel_launch(void* const* d_in, const int* in_sizes, int n_in,
                              void* d_out, int out_size, void* d_ws, size_t ws_size,
                              hipStream_t stream) {
    const float* x     = (const float*)d_in[0];
    const float* W0    = (const float*)d_in[1];
    const float* W1    = (const float*)d_in[2];
    const float* W2    = (const float*)d_in[3];
    const float* out_w = (const float*)d_in[4];
    float* out = (float*)d_out;
    char* ws = (char*)d_ws;

    u64*      enc2   = (u64*)(ws + OFF_ENC2);
    u64*      act2   = (u64*)(ws + OFF_ACT2);
    uint16_t* table  = (uint16_t*)(ws + OFF_TABLE);
    int*      counts = (int*)(ws + OFF_COUNTS);
    short*    wt     = (short*)(ws + OFF_WT);
    float*    part   = (float*)(ws + OFF_PART);

    int use_part = (ws_size >= (size_t)WS_NEED) ? 1 : 0;

    hipLaunchKernelGGL(k_prep, dim3(8704), dim3(256), 0, stream,
                       x, enc2, W0, W1, W2, table, counts, out_w, wt);
    if (!use_part)
        (void)hipMemsetAsync(d_out, 0, (size_t)BATCH * CLS * sizeof(float), stream);

    hipLaunchKernelGGL(k_layer, dim3(8192), dim3(256), 0, stream,
                       enc2, ENC, table, counts, act2);
    hipLaunchKernelGGL(k_layer, dim3(8192), dim3(256), 0, stream,
                       act2, HID, table + (size_t)HID * 32, counts + HID, act2 + 8 * HID);
    hipLaunchKernelGGL(k_layer, dim3(8192), dim3(256), 0, stream,
                       act2 + 8 * HID, HID, table + (size_t)2 * HID * 32, counts + 2 * HID,
                       act2 + 16 * HID);
    if (use_part) {
        hipLaunchKernelGGL((k_gemm<0>), dim3(512), dim3(256), 0, stream,
                           act2, wt, out, part);
        hipLaunchKernelGGL(k_reduce, dim3((BATCH * CLS + 255) / 256), dim3(256), 0, stream,
                           part, out);
    } else {
        hipLaunchKernelGGL((k_gemm<1>), dim3(512), dim3(256), 0, stream,
                           act2, wt, out, part);
    }
}